// Round 1
// baseline (157.735 us; speedup 1.0000x reference)
//
#include <hip/hip_runtime.h>

// Harmonic bond energy: E = sum_b 0.5*k_b*(|r_i - r_j| - b0_b)^2
// Stage 1: grid-stride over bonds, per-block partial sums into d_ws.
// Stage 2: single block reduces partials deterministically into d_out[0].

#define NBLOCKS 2048
#define NTHREADS 256

__global__ __launch_bounds__(NTHREADS) void bond_energy_partials(
    const float* __restrict__ coords,
    const int2* __restrict__ bonds,
    const float* __restrict__ b0,
    const float* __restrict__ kk,
    float* __restrict__ partials,
    int n_bonds)
{
    float acc = 0.0f;
    const int stride = gridDim.x * blockDim.x;
    for (int i = blockIdx.x * blockDim.x + threadIdx.x; i < n_bonds; i += stride) {
        int2 b = bonds[i];
        const float* ri = coords + 3L * (long)b.x;
        const float* rj = coords + 3L * (long)b.y;
        float dx = ri[0] - rj[0];
        float dy = ri[1] - rj[1];
        float dz = ri[2] - rj[2];
        float r = sqrtf(dx * dx + dy * dy + dz * dz);
        float d = r - b0[i];
        acc += 0.5f * kk[i] * d * d;
    }

    // wave64 butterfly reduce
    #pragma unroll
    for (int off = 32; off > 0; off >>= 1)
        acc += __shfl_down(acc, off, 64);

    __shared__ float wsum[NTHREADS / 64];
    const int lane = threadIdx.x & 63;
    const int wid  = threadIdx.x >> 6;
    if (lane == 0) wsum[wid] = acc;
    __syncthreads();
    if (threadIdx.x == 0) {
        float s = 0.0f;
        #pragma unroll
        for (int w = 0; w < NTHREADS / 64; ++w) s += wsum[w];
        partials[blockIdx.x] = s;
    }
}

__global__ __launch_bounds__(NTHREADS) void reduce_partials(
    const float* __restrict__ partials,
    float* __restrict__ out,
    int n)
{
    float acc = 0.0f;
    for (int i = threadIdx.x; i < n; i += NTHREADS) acc += partials[i];

    #pragma unroll
    for (int off = 32; off > 0; off >>= 1)
        acc += __shfl_down(acc, off, 64);

    __shared__ float wsum[NTHREADS / 64];
    const int lane = threadIdx.x & 63;
    const int wid  = threadIdx.x >> 6;
    if (lane == 0) wsum[wid] = acc;
    __syncthreads();
    if (threadIdx.x == 0) {
        float s = 0.0f;
        #pragma unroll
        for (int w = 0; w < NTHREADS / 64; ++w) s += wsum[w];
        out[0] = s;
    }
}

extern "C" void kernel_launch(void* const* d_in, const int* in_sizes, int n_in,
                              void* d_out, int out_size, void* d_ws, size_t ws_size,
                              hipStream_t stream) {
    const float* coords = (const float*)d_in[0];
    // d_in[1] = box (unused by reference math)
    const int2*  bonds  = (const int2*)d_in[2];
    const float* b0     = (const float*)d_in[3];
    const float* kk     = (const float*)d_in[4];
    float* out = (float*)d_out;

    const int n_bonds = in_sizes[2] / 2;
    float* partials = (float*)d_ws;  // NBLOCKS floats = 8 KB

    bond_energy_partials<<<NBLOCKS, NTHREADS, 0, stream>>>(
        coords, bonds, b0, kk, partials, n_bonds);
    reduce_partials<<<1, NTHREADS, 0, stream>>>(partials, out, NBLOCKS);
}

// Round 3
// 156.028 us; speedup vs baseline: 1.0109x; 1.0109x over previous
//
#include <hip/hip_runtime.h>

// Harmonic bond energy: E = sum_b 0.5*k_b*(|r_i - r_j| - b0_b)^2
// R3: 4x unroll for MLP on coord gathers; non-temporal vectorized streaming
// via clang ext_vector types (HIP_vector_type not accepted by the builtin).

#define NBLOCKS 2048
#define NTHREADS 256

typedef int   intx4   __attribute__((ext_vector_type(4)));
typedef float floatx4 __attribute__((ext_vector_type(4)));

__global__ __launch_bounds__(NTHREADS) void bond_energy_partials(
    const float* __restrict__ coords,
    const int*  __restrict__ bonds,   // flat [n_bonds*2]
    const float* __restrict__ b0,
    const float* __restrict__ kk,
    float* __restrict__ partials,
    int n_bonds)
{
    float acc = 0.0f;
    const int tid = blockIdx.x * blockDim.x + threadIdx.x;
    const int nthreads_total = gridDim.x * blockDim.x;
    const int stride4 = nthreads_total * 4;
    const int n4 = (n_bonds / 4) * 4;

    for (int base = tid * 4; base < n4; base += stride4) {
        // Streamed once: non-temporal, vectorized (16B per load).
        intx4 p0 = __builtin_nontemporal_load((const intx4*)(bonds + 2 * base));      // bonds 0,1
        intx4 p1 = __builtin_nontemporal_load((const intx4*)(bonds + 2 * base + 4));  // bonds 2,3
        floatx4 vb0 = __builtin_nontemporal_load((const floatx4*)(b0 + base));
        floatx4 vk  = __builtin_nontemporal_load((const floatx4*)(kk + base));

        const int ia[4] = {p0.x, p0.z, p1.x, p1.z};
        const int ja[4] = {p0.y, p0.w, p1.y, p1.w};

        // Issue all 24 gather dwords before any compute -> high MLP.
        float xi[4][3], xj[4][3];
        #pragma unroll
        for (int u = 0; u < 4; ++u) {
            const float* ri = coords + 3L * (long)ia[u];
            const float* rj = coords + 3L * (long)ja[u];
            xi[u][0] = ri[0]; xi[u][1] = ri[1]; xi[u][2] = ri[2];
            xj[u][0] = rj[0]; xj[u][1] = rj[1]; xj[u][2] = rj[2];
        }

        const float b0s[4] = {vb0.x, vb0.y, vb0.z, vb0.w};
        const float ks[4]  = {vk.x,  vk.y,  vk.z,  vk.w};

        #pragma unroll
        for (int u = 0; u < 4; ++u) {
            float dx = xi[u][0] - xj[u][0];
            float dy = xi[u][1] - xj[u][1];
            float dz = xi[u][2] - xj[u][2];
            float r = sqrtf(dx * dx + dy * dy + dz * dz);
            float d = r - b0s[u];
            acc += 0.5f * ks[u] * d * d;
        }
    }

    // Tail (n_bonds not divisible by 4)
    for (int i = n4 + tid; i < n_bonds; i += nthreads_total) {
        int bi = bonds[2 * i];
        int bj = bonds[2 * i + 1];
        const float* ri = coords + 3L * (long)bi;
        const float* rj = coords + 3L * (long)bj;
        float dx = ri[0] - rj[0];
        float dy = ri[1] - rj[1];
        float dz = ri[2] - rj[2];
        float r = sqrtf(dx * dx + dy * dy + dz * dz);
        float d = r - b0[i];
        acc += 0.5f * kk[i] * d * d;
    }

    // wave64 butterfly reduce
    #pragma unroll
    for (int off = 32; off > 0; off >>= 1)
        acc += __shfl_down(acc, off, 64);

    __shared__ float wsum[NTHREADS / 64];
    const int lane = threadIdx.x & 63;
    const int wid  = threadIdx.x >> 6;
    if (lane == 0) wsum[wid] = acc;
    __syncthreads();
    if (threadIdx.x == 0) {
        float s = 0.0f;
        #pragma unroll
        for (int w = 0; w < NTHREADS / 64; ++w) s += wsum[w];
        partials[blockIdx.x] = s;
    }
}

__global__ __launch_bounds__(NTHREADS) void reduce_partials(
    const float* __restrict__ partials,
    float* __restrict__ out,
    int n)
{
    float acc = 0.0f;
    for (int i = threadIdx.x; i < n; i += NTHREADS) acc += partials[i];

    #pragma unroll
    for (int off = 32; off > 0; off >>= 1)
        acc += __shfl_down(acc, off, 64);

    __shared__ float wsum[NTHREADS / 64];
    const int lane = threadIdx.x & 63;
    const int wid  = threadIdx.x >> 6;
    if (lane == 0) wsum[wid] = acc;
    __syncthreads();
    if (threadIdx.x == 0) {
        float s = 0.0f;
        #pragma unroll
        for (int w = 0; w < NTHREADS / 64; ++w) s += wsum[w];
        out[0] = s;
    }
}

extern "C" void kernel_launch(void* const* d_in, const int* in_sizes, int n_in,
                              void* d_out, int out_size, void* d_ws, size_t ws_size,
                              hipStream_t stream) {
    const float* coords = (const float*)d_in[0];
    // d_in[1] = box (unused by reference math)
    const int*   bonds  = (const int*)d_in[2];
    const float* b0     = (const float*)d_in[3];
    const float* kk     = (const float*)d_in[4];
    float* out = (float*)d_out;

    const int n_bonds = in_sizes[2] / 2;
    float* partials = (float*)d_ws;  // NBLOCKS floats = 8 KB

    bond_energy_partials<<<NBLOCKS, NTHREADS, 0, stream>>>(
        coords, bonds, b0, kk, partials, n_bonds);
    reduce_partials<<<1, NTHREADS, 0, stream>>>(partials, out, NBLOCKS);
}